// Round 3
// baseline (470.796 us; speedup 1.0000x reference)
//
#include <hip/hip_runtime.h>
#include <stdint.h>
#include <math.h>

// x: (32, 256, 56, 56) fp32   W: (256, 256, 3, 3) fp32
// y = conv(sign(x), sign(W), pad=1) -> BN(batch stats) -> Hardtanh
#define N_IMG 32
#define C_IN  256
#define HW    56
#define P_PIX (HW*HW)          // 3136
#define OC    256
#define WPC   8                // 32-bit words per pixel
#define NPIX  (N_IMG*P_PIX)    // 100352
#define NTOT  ((double)N_IMG*(double)P_PIX)

// ---------------------------------------------------------------------------
// 1) Bit-pack activations, float4 reads. px[n][p][word]; bit k of word w =
//    (x[n][32w+k][p] >= 0). Block 784 zeroes the shared zero_row.
__global__ __launch_bounds__(256) void pack_x_kernel(const float* __restrict__ x,
                                                     uint32_t* __restrict__ px,
                                                     uint32_t* __restrict__ zero_row) {
    int blk = blockIdx.x;
    if (blk == 784) {
        if (threadIdx.x < 112) ((uint4*)zero_row)[threadIdx.x] = make_uint4(0u,0u,0u,0u);
        return;
    }
    int idx  = blk * 256 + threadIdx.x;      // 0 .. 200703
    int word = idx / 25088;                  // 0..7
    int r    = idx - word * 25088;
    int n    = r / 784;
    int p4   = r - n * 784;                  // float4 index within image (56%4==0: no row cross)
    const float* xp = x + ((size_t)(n * C_IN + word * 32)) * P_PIX + p4 * 4;
    uint32_t b0 = 0, b1 = 0, b2 = 0, b3 = 0;
#pragma unroll
    for (int k = 0; k < 32; ++k) {
        float4 v = *(const float4*)(xp + (size_t)k * P_PIX);
        b0 |= (v.x >= 0.0f) ? (1u << k) : 0u;
        b1 |= (v.y >= 0.0f) ? (1u << k) : 0u;
        b2 |= (v.z >= 0.0f) ? (1u << k) : 0u;
        b3 |= (v.w >= 0.0f) ? (1u << k) : 0u;
    }
    uint32_t* dst = px + ((size_t)(n * P_PIX + p4 * 4)) * WPC + word;
    dst[0]  = b0;
    dst[8]  = b1;
    dst[16] = b2;
    dst[24] = b3;
}

// ---------------------------------------------------------------------------
// 2) Bit-pack weights (wp[o][72], t = tap*8+word) + border-correction table
//    corr[o][cfg], cfg = vc*3+hc; zero the stat accumulators.
__global__ void pack_w_kernel(const float* __restrict__ Wt,
                              uint32_t* __restrict__ wp,
                              int* __restrict__ corr,
                              long long* __restrict__ sums,
                              long long* __restrict__ sumsq) {
    __shared__ int lpop[72];
    __shared__ int ltap[9];
    int o = blockIdx.x;
    int t = threadIdx.x;     // 128 threads
    if (t == 0) { sums[o] = 0; sumsq[o] = 0; }
    if (t < 72) {
        int tap = t >> 3;
        int word = t & 7;
        const float* wpr = Wt + ((size_t)(o * C_IN + word * 32)) * 9 + tap;
        uint32_t bits = 0;
#pragma unroll
        for (int k = 0; k < 32; ++k) {
            float v = wpr[(size_t)k * 9];
            bits |= (v >= 0.0f) ? (1u << k) : 0u;
        }
        wp[o * 72 + t] = bits;
        lpop[t] = __popc(bits);
    }
    __syncthreads();
    if (t < 9) {
        int s = 0;
#pragma unroll
        for (int w = 0; w < 8; ++w) s += lpop[t * 8 + w];
        ltap[t] = s;
    }
    __syncthreads();
    if (t < 9) {
        int vc = t / 3, hc = t % 3;   // 0=interior, 1=low edge, 2=high edge
        int c = 0;
        for (int dy = -1; dy <= 1; ++dy)
            for (int dx = -1; dx <= 1; ++dx) {
                bool inv = (dy == -1 && vc == 1) || (dy == 1 && vc == 2) ||
                           (dx == -1 && hc == 1) || (dx == 1 && hc == 2);
                if (inv) {
                    int tap = (dy + 1) * 3 + (dx + 1);
                    c += 256 - 2 * ltap[tap];
                }
            }
        corr[o * 9 + t] = c;
    }
}

// ---------------------------------------------------------------------------
// 72-word xor-popcount dot with 4 independent accumulator chains.
__device__ __forceinline__ int dot72(const uint32_t* p0, const uint32_t* p1, const uint32_t* p2,
                                     const uint32_t* p3, const uint32_t* p4, const uint32_t* p5,
                                     const uint32_t* p6, const uint32_t* p7, const uint32_t* p8,
                                     const uint32_t* wreg) {
    const uint32_t* ps[9] = {p0, p1, p2, p3, p4, p5, p6, p7, p8};
    int a0 = 0, a1 = 0, a2 = 0, a3 = 0;
#pragma unroll
    for (int t = 0; t < 9; ++t) {
        uint4 a = ((const uint4*)ps[t])[0];
        uint4 b = ((const uint4*)ps[t])[1];
        a0 += __popc(a.x ^ wreg[t * 8 + 0]);
        a1 += __popc(a.y ^ wreg[t * 8 + 1]);
        a2 += __popc(a.z ^ wreg[t * 8 + 2]);
        a3 += __popc(a.w ^ wreg[t * 8 + 3]);
        a0 += __popc(b.x ^ wreg[t * 8 + 4]);
        a1 += __popc(b.y ^ wreg[t * 8 + 5]);
        a2 += __popc(b.z ^ wreg[t * 8 + 6]);
        a3 += __popc(b.w ^ wreg[t * 8 + 7]);
    }
    return a0 + a1 + a2 + a3;
}

// ---------------------------------------------------------------------------
// 3) Binary conv, lane = output channel (o = threadIdx.x, 4 waves x 64).
//    Weights stationary in 72 VGPRs/lane; block walks one pixel row (n,h).
//    x-words are wave-uniform broadcast loads. Stats accumulate per-lane in
//    registers (s:int32, q:int32 — row maxima 129k / 2.97e8 both fit), one
//    global int64 atomic per lane at the end. y stored transposed [p][o].
__global__ __launch_bounds__(256, 2) void bconv_kernel(const uint32_t* __restrict__ px,
                                                       const uint32_t* __restrict__ wp,
                                                       const int* __restrict__ corr,
                                                       const uint32_t* __restrict__ zero_row,
                                                       short* __restrict__ y16t,
                                                       long long* __restrict__ sums,
                                                       long long* __restrict__ sumsq) {
    int o   = threadIdx.x;
    int blk = blockIdx.x;           // 0..1791
    int n = blk / HW, h = blk - n * HW;

    uint32_t wreg[72];
    const uint4* wq = (const uint4*)(wp + o * 72);
#pragma unroll
    for (int j = 0; j < 18; ++j) {
        uint4 v = wq[j];
        wreg[4 * j + 0] = v.x; wreg[4 * j + 1] = v.y;
        wreg[4 * j + 2] = v.z; wreg[4 * j + 3] = v.w;
    }
    int vc  = (h == 0) ? 1 : ((h == HW - 1) ? 2 : 0);
    int crM = corr[o * 9 + vc * 3 + 0];
    int crL = corr[o * 9 + vc * 3 + 1];
    int crR = corr[o * 9 + vc * 3 + 2];

    const uint32_t* rowb = px + (size_t)(n * P_PIX) * WPC;
    const uint32_t* rp0 = (h > 0)      ? rowb + (h - 1) * HW * WPC : zero_row;
    const uint32_t* rp1 = rowb + h * HW * WPC;
    const uint32_t* rp2 = (h < HW - 1) ? rowb + (h + 1) * HW * WPC : zero_row;

    short* yp = y16t + ((size_t)(n * P_PIX + h * HW)) * OC + o;
    int s = 0, q = 0;

    // w = 0 (left column zero)
    {
        int acc = dot72(zero_row, rp0, rp0 + 8,
                        zero_row, rp1, rp1 + 8,
                        zero_row, rp2, rp2 + 8, wreg);
        int v = 2304 - 2 * acc - crL;
        yp[0] = (short)v;
        s += v; q += __mul24(v, v);
    }
    // interior w = 1..54
    const uint32_t* c0 = rp0;
    const uint32_t* c1 = rp1;
    const uint32_t* c2 = rp2;
    for (int w = 1; w <= HW - 2; ++w) {
        c0 += 8; c1 += 8; c2 += 8;      // now at col w
        int acc = dot72(c0 - 8, c0, c0 + 8,
                        c1 - 8, c1, c1 + 8,
                        c2 - 8, c2, c2 + 8, wreg);
        int v = 2304 - 2 * acc - crM;
        yp[(size_t)w * OC] = (short)v;
        s += v; q += __mul24(v, v);
    }
    // w = 55 (right column zero)
    {
        const uint32_t* e0 = rp0 + (HW - 1) * 8;
        const uint32_t* e1 = rp1 + (HW - 1) * 8;
        const uint32_t* e2 = rp2 + (HW - 1) * 8;
        int acc = dot72(e0 - 8, e0, zero_row,
                        e1 - 8, e1, zero_row,
                        e2 - 8, e2, zero_row, wreg);
        int v = 2304 - 2 * acc - crR;
        yp[(size_t)(HW - 1) * OC] = (short)v;
        s += v; q += __mul24(v, v);
    }
    atomicAdd((unsigned long long*)&sums[o],  (unsigned long long)(long long)s);
    atomicAdd((unsigned long long*)&sumsq[o], (unsigned long long)(long long)q);
}

// ---------------------------------------------------------------------------
// 4) Fused BN + Hardtanh + transpose back to NCHW through LDS.
//    Block = 64 pixels x 256 channels (49 blocks per image, never crosses n).
__global__ __launch_bounds__(256) void apply_kernel(const short* __restrict__ y16t,
                                                    float* __restrict__ out,
                                                    const long long* __restrict__ sums,
                                                    const long long* __restrict__ sumsq,
                                                    const float* __restrict__ gamma,
                                                    const float* __restrict__ beta) {
    __shared__ float sbf[512];               // scale[256] | bias[256]
    __shared__ uint32_t tile[64 * 129];      // short2-packed [px][ch/2], stride 129 dwords
    int t = threadIdx.x;
    {
        int o = t;
        double invN = 1.0 / NTOT;
        double mean = (double)sums[o] * invN;
        double var  = (double)sumsq[o] * invN - mean * mean;
        double sc   = (double)gamma[o] / sqrt(var + 1e-5);
        sbf[o]       = (float)sc;
        sbf[256 + o] = (float)((double)beta[o] - mean * sc);
    }
    int blk = blockIdx.x;                    // 0..1567
    int n   = blk / 49;
    int pl0 = (blk - n * 49) * 64;
    size_t P0 = (size_t)n * P_PIX + pl0;
    // phase A: load 64 px x 256 ch (coalesced short8), scatter into LDS as dwords
#pragma unroll
    for (int r = 0; r < 8; ++r) {
        int f8  = r * 256 + t;               // short8 units
        int pxl = f8 >> 5;
        int c8  = f8 & 31;
        uint4 v = *(const uint4*)(y16t + (P0 + pxl) * OC + c8 * 8);
        uint32_t* d = &tile[pxl * 129 + c8 * 4];
        d[0] = v.x; d[1] = v.y; d[2] = v.z; d[3] = v.w;
    }
    __syncthreads();
    // phase B: lane l -> ch = i*16 + wave*4 + l/16, px-quad = (l&15)*4
    int lane = t & 63, wv = t >> 6;
    int lp = lane & 15, lc = lane >> 4;
    int px0 = lp * 4;
#pragma unroll
    for (int i = 0; i < 16; ++i) {
        int ch = i * 16 + wv * 4 + lc;
        float sc = sbf[ch], bi = sbf[256 + ch];
        int sh = (ch & 1) << 4;
        int ci = ch >> 1;
        float4 ov;
        {
            int v0 = (int)(short)(tile[(px0 + 0) * 129 + ci] >> sh);
            int v1 = (int)(short)(tile[(px0 + 1) * 129 + ci] >> sh);
            int v2 = (int)(short)(tile[(px0 + 2) * 129 + ci] >> sh);
            int v3 = (int)(short)(tile[(px0 + 3) * 129 + ci] >> sh);
            ov.x = fminf(fmaxf(fmaf((float)v0, sc, bi), -1.0f), 1.0f);
            ov.y = fminf(fmaxf(fmaf((float)v1, sc, bi), -1.0f), 1.0f);
            ov.z = fminf(fmaxf(fmaf((float)v2, sc, bi), -1.0f), 1.0f);
            ov.w = fminf(fmaxf(fmaf((float)v3, sc, bi), -1.0f), 1.0f);
        }
        *(float4*)(out + ((size_t)(n * OC + ch)) * P_PIX + pl0 + px0) = ov;
    }
}

// ---------------------------------------------------------------------------
extern "C" void kernel_launch(void* const* d_in, const int* in_sizes, int n_in,
                              void* d_out, int out_size, void* d_ws, size_t ws_size,
                              hipStream_t stream) {
    const float* x     = (const float*)d_in[0];
    const float* Wt    = (const float*)d_in[1];
    const float* gamma = (const float*)d_in[2];
    const float* beta  = (const float*)d_in[3];
    float* out = (float*)d_out;
    char* ws = (char*)d_ws;

    // Workspace layout (total 54,680,576 B <= proven-available 54,686,720 B)
    uint32_t*  px       = (uint32_t*) (ws);              // 3,211,264
    uint32_t*  wp       = (uint32_t*) (ws + 3211264);    //    73,728
    int*       corr     = (int*)      (ws + 3284992);    //     9,216
    long long* sums     = (long long*)(ws + 3294208);    //     2,048
    long long* sumsq    = (long long*)(ws + 3296256);    //     2,048
    uint32_t*  zero_row = (uint32_t*) (ws + 3298304);    //     2,048 (1792 used)
    short*     y16t     = (short*)    (ws + 3300352);    // 51,380,224

    hipLaunchKernelGGL(pack_x_kernel, dim3(785),  dim3(256), 0, stream, x, px, zero_row);
    hipLaunchKernelGGL(pack_w_kernel, dim3(OC),   dim3(128), 0, stream, Wt, wp, corr, sums, sumsq);
    hipLaunchKernelGGL(bconv_kernel,  dim3(1792), dim3(256), 0, stream, px, wp, corr, zero_row,
                       y16t, sums, sumsq);
    hipLaunchKernelGGL(apply_kernel,  dim3(1568), dim3(256), 0, stream, y16t, out,
                       sums, sumsq, gamma, beta);
}

// Round 5
// 356.978 us; speedup vs baseline: 1.3188x; 1.3188x over previous
//
#include <hip/hip_runtime.h>
#include <stdint.h>
#include <math.h>

// x: (32, 256, 56, 56) fp32   W: (256, 256, 3, 3) fp32
// y = conv(sign(x), sign(W), pad=1) -> BN(batch stats) -> Hardtanh
// (Round-4 resubmission of round-3 source: bench infra failed, no data.)
#define N_IMG 32
#define C_IN  256
#define HW    56
#define P_PIX (HW*HW)          // 3136
#define OC    256
#define WPC   8                // 32-bit words per pixel
#define NPIX  (N_IMG*P_PIX)    // 100352
#define NTOT  ((double)N_IMG*(double)P_PIX)

// ---------------------------------------------------------------------------
// 1) Bit-pack activations. Thread = (pixel-quad, word-half); wh = wave index so
//    each load instr reads 64 lanes x 16B = 1KB contiguous. Block 392 zeroes
//    zero_row (448 dwords).
__global__ __launch_bounds__(256) void pack_x_kernel(const float* __restrict__ x,
                                                     uint32_t* __restrict__ px,
                                                     uint32_t* __restrict__ zero_row) {
    if (blockIdx.x == 392) {
        if (threadIdx.x < 224) ((uint2*)zero_row)[threadIdx.x] = make_uint2(0u, 0u);
        return;
    }
    int lane = threadIdx.x & 63;
    int wh   = threadIdx.x >> 6;                 // word-half 0..3 (channels wh*64..wh*64+63)
    int pq   = blockIdx.x * 64 + lane;           // global pixel-quad 0..25087
    int n    = pq / 784;
    int q    = pq - n * 784;                     // quad within image; pixels q*4..q*4+3
    const float* xp = x + ((size_t)(n * C_IN + wh * 64)) * P_PIX + q * 4;
    uint32_t b0[4] = {0, 0, 0, 0};
    uint32_t b1[4] = {0, 0, 0, 0};
#pragma unroll 8
    for (int i = 0; i < 32; ++i) {
        float4 v = *(const float4*)(xp + (size_t)i * P_PIX);
        uint32_t bit = 1u << i;
        b0[0] |= (v.x >= 0.0f) ? bit : 0u;
        b0[1] |= (v.y >= 0.0f) ? bit : 0u;
        b0[2] |= (v.z >= 0.0f) ? bit : 0u;
        b0[3] |= (v.w >= 0.0f) ? bit : 0u;
    }
#pragma unroll 8
    for (int i = 0; i < 32; ++i) {
        float4 v = *(const float4*)(xp + (size_t)(i + 32) * P_PIX);
        uint32_t bit = 1u << i;
        b1[0] |= (v.x >= 0.0f) ? bit : 0u;
        b1[1] |= (v.y >= 0.0f) ? bit : 0u;
        b1[2] |= (v.z >= 0.0f) ? bit : 0u;
        b1[3] |= (v.w >= 0.0f) ? bit : 0u;
    }
    uint32_t* dst = px + ((size_t)(n * P_PIX + q * 4)) * WPC + wh * 2;
    *(uint2*)(dst + 0)  = make_uint2(b0[0], b1[0]);
    *(uint2*)(dst + 8)  = make_uint2(b0[1], b1[1]);
    *(uint2*)(dst + 16) = make_uint2(b0[2], b1[2]);
    *(uint2*)(dst + 24) = make_uint2(b0[3], b1[3]);
}

// ---------------------------------------------------------------------------
// 2) Bit-pack weights (wp[o][72], t = tap*8+word) + border-correction table
//    corr[o][cfg], cfg = vc*3+hc; zero the stat accumulators.
__global__ void pack_w_kernel(const float* __restrict__ Wt,
                              uint32_t* __restrict__ wp,
                              int* __restrict__ corr,
                              long long* __restrict__ sums,
                              long long* __restrict__ sumsq) {
    __shared__ int lpop[72];
    __shared__ int ltap[9];
    int o = blockIdx.x;
    int t = threadIdx.x;     // 128 threads
    if (t == 0) { sums[o] = 0; sumsq[o] = 0; }
    if (t < 72) {
        int tap = t >> 3;
        int word = t & 7;
        const float* wpr = Wt + ((size_t)(o * C_IN + word * 32)) * 9 + tap;
        uint32_t bits = 0;
#pragma unroll
        for (int k = 0; k < 32; ++k) {
            float v = wpr[(size_t)k * 9];
            bits |= (v >= 0.0f) ? (1u << k) : 0u;
        }
        wp[o * 72 + t] = bits;
        lpop[t] = __popc(bits);
    }
    __syncthreads();
    if (t < 9) {
        int s = 0;
#pragma unroll
        for (int w = 0; w < 8; ++w) s += lpop[t * 8 + w];
        ltap[t] = s;
    }
    __syncthreads();
    if (t < 9) {
        int vc = t / 3, hc = t % 3;   // 0=interior, 1=low edge, 2=high edge
        int c = 0;
        for (int dy = -1; dy <= 1; ++dy)
            for (int dx = -1; dx <= 1; ++dx) {
                bool inv = (dy == -1 && vc == 1) || (dy == 1 && vc == 2) ||
                           (dx == -1 && hc == 1) || (dx == 1 && hc == 2);
                if (inv) {
                    int tap = (dy + 1) * 3 + (dx + 1);
                    c += 256 - 2 * ltap[tap];
                }
            }
        corr[o * 9 + t] = c;
    }
}

// ---------------------------------------------------------------------------
// 3) Binary conv, lane = output channel. Weights stationary in 72 VGPRs/lane.
//    x-window: 4 column slots (A,B,C,D) of 3 rows x 8 words each, in VGPRs,
//    rotated by unroll (no movs). Each step loads only the new column (6
//    dwordx4), issued one full dot (~660 cy) before first use -> compiler's
//    counted vmcnt keeps latency hidden. Per-lane stats, one int64 atomic pair
//    per lane per row. y stored transposed [pixel][o] as int16.
#define LOADCOL(S, c) do {                                                    \
    int _c = (c);                                                             \
    const uint32_t* _p0 = ((unsigned)_c < 56u) ? (r0 + _c * 8) : zero_row;    \
    const uint32_t* _p1 = ((unsigned)_c < 56u) ? (r1 + _c * 8) : zero_row;    \
    const uint32_t* _p2 = ((unsigned)_c < 56u) ? (r2 + _c * 8) : zero_row;    \
    x0##S##a = *(const uint4*)_p0; x0##S##b = *(const uint4*)(_p0 + 4);       \
    x1##S##a = *(const uint4*)_p1; x1##S##b = *(const uint4*)(_p1 + 4);       \
    x2##S##a = *(const uint4*)_p2; x2##S##b = *(const uint4*)(_p2 + 4);       \
} while (0)

#define TAP(va, vb, t)                                                        \
    a0 += __popc((va).x ^ wreg[(t)*8+0]); a1 += __popc((va).y ^ wreg[(t)*8+1]); \
    a2 += __popc((va).z ^ wreg[(t)*8+2]); a3 += __popc((va).w ^ wreg[(t)*8+3]); \
    a0 += __popc((vb).x ^ wreg[(t)*8+4]); a1 += __popc((vb).y ^ wreg[(t)*8+5]); \
    a2 += __popc((vb).z ^ wreg[(t)*8+6]); a3 += __popc((vb).w ^ wreg[(t)*8+7]);

// STEP computes pixel w using slots (M=w-1, Cc=w, P=w+1), then prefetches
// column w+3 into slot M (dead after this dot).
#define STEP(M, Cc, P, w, yptr) do {                                          \
    int a0 = 0, a1 = 0, a2 = 0, a3 = 0;                                       \
    TAP(x0##M##a,  x0##M##b,  0) TAP(x0##Cc##a, x0##Cc##b, 1) TAP(x0##P##a, x0##P##b, 2) \
    TAP(x1##M##a,  x1##M##b,  3) TAP(x1##Cc##a, x1##Cc##b, 4) TAP(x1##P##a, x1##P##b, 5) \
    TAP(x2##M##a,  x2##M##b,  6) TAP(x2##Cc##a, x2##Cc##b, 7) TAP(x2##P##a, x2##P##b, 8) \
    int acc = (a0 + a1) + (a2 + a3);                                          \
    int cr  = ((w) == 0) ? crL : (((w) == HW - 1) ? crR : crM);               \
    int v   = 2304 - 2 * acc - cr;                                            \
    *(yptr) = (short)v;                                                       \
    s += v; q += __mul24(v, v);                                               \
    LOADCOL(M, (w) + 3);                                                      \
} while (0)

__global__ __launch_bounds__(256, 2) void bconv_kernel(const uint32_t* __restrict__ px,
                                                       const uint32_t* __restrict__ wp,
                                                       const int* __restrict__ corr,
                                                       const uint32_t* __restrict__ zero_row,
                                                       short* __restrict__ y16t,
                                                       long long* __restrict__ sums,
                                                       long long* __restrict__ sumsq) {
    int o   = threadIdx.x;          // output channel 0..255
    int blk = blockIdx.x;           // 0..1791
    int n = blk / HW, h = blk - n * HW;

    uint32_t wreg[72];
    {
        const uint4* wq = (const uint4*)(wp + o * 72);
#pragma unroll
        for (int j = 0; j < 18; ++j) {
            uint4 t4 = wq[j];
            wreg[4*j+0] = t4.x; wreg[4*j+1] = t4.y;
            wreg[4*j+2] = t4.z; wreg[4*j+3] = t4.w;
        }
    }
    int vc  = (h == 0) ? 1 : ((h == HW - 1) ? 2 : 0);
    int crM = corr[o * 9 + vc * 3 + 0];
    int crL = corr[o * 9 + vc * 3 + 1];
    int crR = corr[o * 9 + vc * 3 + 2];

    const uint32_t* rowb = px + (size_t)(n * P_PIX) * WPC;
    const uint32_t* r0 = (h > 0)      ? rowb + (h - 1) * HW * WPC : zero_row;
    const uint32_t* r1 = rowb + h * HW * WPC;
    const uint32_t* r2 = (h < HW - 1) ? rowb + (h + 1) * HW * WPC : zero_row;

    uint4 x0Aa, x0Ab, x1Aa, x1Ab, x2Aa, x2Ab;
    uint4 x0Ba, x0Bb, x1Ba, x1Bb, x2Ba, x2Bb;
    uint4 x0Ca, x0Cb, x1Ca, x1Cb, x2Ca, x2Cb;
    uint4 x0Da, x0Db, x1Da, x1Db, x2Da, x2Db;

    LOADCOL(A, -1);     // zeros (left halo)
    LOADCOL(B, 0);
    LOADCOL(C, 1);
    LOADCOL(D, 2);      // in flight across first dot

    short* yw = y16t + ((size_t)(n * P_PIX + h * HW)) * OC + o;
    int s = 0, q = 0;

    for (int wb = 0; wb < HW; wb += 4) {
        STEP(A, B, C, wb + 0, yw);
        STEP(B, C, D, wb + 1, yw + OC);
        STEP(C, D, A, wb + 2, yw + 2 * OC);
        STEP(D, A, B, wb + 3, yw + 3 * OC);
        yw += 4 * OC;
    }

    atomicAdd((unsigned long long*)&sums[o],  (unsigned long long)(long long)s);
    atomicAdd((unsigned long long*)&sumsq[o], (unsigned long long)(long long)q);
}

// ---------------------------------------------------------------------------
// 4) Fused BN + Hardtanh + transpose back to NCHW through LDS.
//    Block = 64 pixels x 256 channels (49 blocks per image, never crosses n).
__global__ __launch_bounds__(256) void apply_kernel(const short* __restrict__ y16t,
                                                    float* __restrict__ out,
                                                    const long long* __restrict__ sums,
                                                    const long long* __restrict__ sumsq,
                                                    const float* __restrict__ gamma,
                                                    const float* __restrict__ beta) {
    __shared__ float sbf[512];               // scale[256] | bias[256]
    __shared__ uint32_t tile[64 * 129];      // short2-packed [px][ch/2], stride 129 dwords
    int t = threadIdx.x;
    {
        int o = t;
        double invN = 1.0 / NTOT;
        double mean = (double)sums[o] * invN;
        double var  = (double)sumsq[o] * invN - mean * mean;
        double sc   = (double)gamma[o] / sqrt(var + 1e-5);
        sbf[o]       = (float)sc;
        sbf[256 + o] = (float)((double)beta[o] - mean * sc);
    }
    int blk = blockIdx.x;                    // 0..1567
    int n   = blk / 49;
    int pl0 = (blk - n * 49) * 64;
    size_t P0 = (size_t)n * P_PIX + pl0;
    // phase A: load 64 px x 256 ch (coalesced short8), scatter into LDS as dwords
#pragma unroll
    for (int r = 0; r < 8; ++r) {
        int f8  = r * 256 + t;               // short8 units
        int pxl = f8 >> 5;
        int c8  = f8 & 31;
        uint4 v = *(const uint4*)(y16t + (P0 + pxl) * OC + c8 * 8);
        uint32_t* d = &tile[pxl * 129 + c8 * 4];
        d[0] = v.x; d[1] = v.y; d[2] = v.z; d[3] = v.w;
    }
    __syncthreads();
    // phase B: lane l -> ch = i*16 + wave*4 + l/16, px-quad = (l&15)*4
    int lane = t & 63, wv = t >> 6;
    int lp = lane & 15, lc = lane >> 4;
    int px0 = lp * 4;
#pragma unroll
    for (int i = 0; i < 16; ++i) {
        int ch = i * 16 + wv * 4 + lc;
        float sc = sbf[ch], bi = sbf[256 + ch];
        int sh = (ch & 1) << 4;
        int ci = ch >> 1;
        float4 ov;
        {
            int v0 = (int)(short)(tile[(px0 + 0) * 129 + ci] >> sh);
            int v1 = (int)(short)(tile[(px0 + 1) * 129 + ci] >> sh);
            int v2 = (int)(short)(tile[(px0 + 2) * 129 + ci] >> sh);
            int v3 = (int)(short)(tile[(px0 + 3) * 129 + ci] >> sh);
            ov.x = fminf(fmaxf(fmaf((float)v0, sc, bi), -1.0f), 1.0f);
            ov.y = fminf(fmaxf(fmaf((float)v1, sc, bi), -1.0f), 1.0f);
            ov.z = fminf(fmaxf(fmaf((float)v2, sc, bi), -1.0f), 1.0f);
            ov.w = fminf(fmaxf(fmaf((float)v3, sc, bi), -1.0f), 1.0f);
        }
        *(float4*)(out + ((size_t)(n * OC + ch)) * P_PIX + pl0 + px0) = ov;
    }
}

// ---------------------------------------------------------------------------
extern "C" void kernel_launch(void* const* d_in, const int* in_sizes, int n_in,
                              void* d_out, int out_size, void* d_ws, size_t ws_size,
                              hipStream_t stream) {
    const float* x     = (const float*)d_in[0];
    const float* Wt    = (const float*)d_in[1];
    const float* gamma = (const float*)d_in[2];
    const float* beta  = (const float*)d_in[3];
    float* out = (float*)d_out;
    char* ws = (char*)d_ws;

    // Workspace layout (total 54,680,576 B — proven available in round 3)
    uint32_t*  px       = (uint32_t*) (ws);              // 3,211,264
    uint32_t*  wp       = (uint32_t*) (ws + 3211264);    //    73,728
    int*       corr     = (int*)      (ws + 3284992);    //     9,216
    long long* sums     = (long long*)(ws + 3294208);    //     2,048
    long long* sumsq    = (long long*)(ws + 3296256);    //     2,048
    uint32_t*  zero_row = (uint32_t*) (ws + 3298304);    //     2,048 (1792 used)
    short*     y16t     = (short*)    (ws + 3300352);    // 51,380,224

    hipLaunchKernelGGL(pack_x_kernel, dim3(393),  dim3(256), 0, stream, x, px, zero_row);
    hipLaunchKernelGGL(pack_w_kernel, dim3(OC),   dim3(128), 0, stream, Wt, wp, corr, sums, sumsq);
    hipLaunchKernelGGL(bconv_kernel,  dim3(1792), dim3(256), 0, stream, px, wp, corr, zero_row,
                       y16t, sums, sumsq);
    hipLaunchKernelGGL(apply_kernel,  dim3(1568), dim3(256), 0, stream, y16t, out,
                       sums, sumsq, gamma, beta);
}

// Round 6
// 337.403 us; speedup vs baseline: 1.3954x; 1.0580x over previous
//
#include <hip/hip_runtime.h>
#include <stdint.h>
#include <math.h>

// x: (32, 256, 56, 56) fp32   W: (256, 256, 3, 3) fp32
// y = conv(sign(x), sign(W), pad=1) -> BN(batch stats) -> Hardtanh
#define N_IMG 32
#define C_IN  256
#define HW    56
#define P_PIX (HW*HW)          // 3136
#define OC    256
#define WPC   8                // 32-bit words per pixel
#define NPIX  (N_IMG*P_PIX)    // 100352
#define NTOT  ((double)N_IMG*(double)P_PIX)

// ---------------------------------------------------------------------------
// 1) Bit-pack activations. Thread = (pixel-quad, word-half); wh = wave index so
//    each load instr reads 64 lanes x 16B = 1KB contiguous. Block 392 zeroes
//    zero_row (448 dwords).
__global__ __launch_bounds__(256) void pack_x_kernel(const float* __restrict__ x,
                                                     uint32_t* __restrict__ px,
                                                     uint32_t* __restrict__ zero_row) {
    if (blockIdx.x == 392) {
        if (threadIdx.x < 224) ((uint2*)zero_row)[threadIdx.x] = make_uint2(0u, 0u);
        return;
    }
    int lane = threadIdx.x & 63;
    int wh   = threadIdx.x >> 6;                 // word-half 0..3 (channels wh*64..wh*64+63)
    int pq   = blockIdx.x * 64 + lane;           // global pixel-quad 0..25087
    int n    = pq / 784;
    int q    = pq - n * 784;                     // quad within image; pixels q*4..q*4+3
    const float* xp = x + ((size_t)(n * C_IN + wh * 64)) * P_PIX + q * 4;
    uint32_t b0[4] = {0, 0, 0, 0};
    uint32_t b1[4] = {0, 0, 0, 0};
#pragma unroll 8
    for (int i = 0; i < 32; ++i) {
        float4 v = *(const float4*)(xp + (size_t)i * P_PIX);
        uint32_t bit = 1u << i;
        b0[0] |= (v.x >= 0.0f) ? bit : 0u;
        b0[1] |= (v.y >= 0.0f) ? bit : 0u;
        b0[2] |= (v.z >= 0.0f) ? bit : 0u;
        b0[3] |= (v.w >= 0.0f) ? bit : 0u;
    }
#pragma unroll 8
    for (int i = 0; i < 32; ++i) {
        float4 v = *(const float4*)(xp + (size_t)(i + 32) * P_PIX);
        uint32_t bit = 1u << i;
        b1[0] |= (v.x >= 0.0f) ? bit : 0u;
        b1[1] |= (v.y >= 0.0f) ? bit : 0u;
        b1[2] |= (v.z >= 0.0f) ? bit : 0u;
        b1[3] |= (v.w >= 0.0f) ? bit : 0u;
    }
    uint32_t* dst = px + ((size_t)(n * P_PIX + q * 4)) * WPC + wh * 2;
    *(uint2*)(dst + 0)  = make_uint2(b0[0], b1[0]);
    *(uint2*)(dst + 8)  = make_uint2(b0[1], b1[1]);
    *(uint2*)(dst + 16) = make_uint2(b0[2], b1[2]);
    *(uint2*)(dst + 24) = make_uint2(b0[3], b1[3]);
}

// ---------------------------------------------------------------------------
// 2) Bit-pack weights (wp[o][72], t = tap*8+word) + border-correction table
//    corr[o][cfg], cfg = vc*3+hc; zero the stat accumulators.
__global__ void pack_w_kernel(const float* __restrict__ Wt,
                              uint32_t* __restrict__ wp,
                              int* __restrict__ corr,
                              long long* __restrict__ sums,
                              long long* __restrict__ sumsq) {
    __shared__ int lpop[72];
    __shared__ int ltap[9];
    int o = blockIdx.x;
    int t = threadIdx.x;     // 128 threads
    if (t == 0) { sums[o] = 0; sumsq[o] = 0; }
    if (t < 72) {
        int tap = t >> 3;
        int word = t & 7;
        const float* wpr = Wt + ((size_t)(o * C_IN + word * 32)) * 9 + tap;
        uint32_t bits = 0;
#pragma unroll
        for (int k = 0; k < 32; ++k) {
            float v = wpr[(size_t)k * 9];
            bits |= (v >= 0.0f) ? (1u << k) : 0u;
        }
        wp[o * 72 + t] = bits;
        lpop[t] = __popc(bits);
    }
    __syncthreads();
    if (t < 9) {
        int s = 0;
#pragma unroll
        for (int w = 0; w < 8; ++w) s += lpop[t * 8 + w];
        ltap[t] = s;
    }
    __syncthreads();
    if (t < 9) {
        int vc = t / 3, hc = t % 3;   // 0=interior, 1=low edge, 2=high edge
        int c = 0;
        for (int dy = -1; dy <= 1; ++dy)
            for (int dx = -1; dx <= 1; ++dx) {
                bool inv = (dy == -1 && vc == 1) || (dy == 1 && vc == 2) ||
                           (dx == -1 && hc == 1) || (dx == 1 && hc == 2);
                if (inv) {
                    int tap = (dy + 1) * 3 + (dx + 1);
                    c += 256 - 2 * ltap[tap];
                }
            }
        corr[o * 9 + t] = c;
    }
}

// ---------------------------------------------------------------------------
// 3) Binary conv, lane = output channel. Weights stationary in 72 VGPRs/lane.
//    The 3 needed x-rows are staged ONCE per block into LDS (shared by all 4
//    waves), with halo columns 0 and 57 pre-zeroed -> branch-free inner loop.
//    Window reads are wave-uniform ds_read_b128 (broadcast, conflict-free,
//    lgkm pipe overlaps VALU). 3-slot rotation, w=0 / w=55 peeled so the
//    interior 54 steps use a constant crM. Per-lane stats in registers
//    (row maxima: |s|<=129K, q<=297M — int32 safe), one int64 atomic pair per
//    lane per row. y stored transposed [pixel][o] as int16.
#define XS_COLS 58          // 56 + 2 halo
// slot S in {A,B,C}; cslot = halo-shifted column slot (global col c -> slot c+1)
#define LOADCOL(S, cslot) do {                                                \
    int _c2 = (cslot) * 2;                                                    \
    x0##S##a = xs[0][_c2]; x0##S##b = xs[0][_c2 + 1];                         \
    x1##S##a = xs[1][_c2]; x1##S##b = xs[1][_c2 + 1];                         \
    x2##S##a = xs[2][_c2]; x2##S##b = xs[2][_c2 + 1];                         \
} while (0)

#define TAP(va, vb, t)                                                        \
    a0 += __popc((va).x ^ wreg[(t)*8+0]); a1 += __popc((va).y ^ wreg[(t)*8+1]); \
    a2 += __popc((va).z ^ wreg[(t)*8+2]); a3 += __popc((va).w ^ wreg[(t)*8+3]); \
    a0 += __popc((vb).x ^ wreg[(t)*8+4]); a1 += __popc((vb).y ^ wreg[(t)*8+5]); \
    a2 += __popc((vb).z ^ wreg[(t)*8+6]); a3 += __popc((vb).w ^ wreg[(t)*8+7]);

// STEP computes one pixel from slots (M=w-1, Cc=w, P=w+1).
#define STEP(M, Cc, P, cr, yptr) do {                                         \
    int a0 = 0, a1 = 0, a2 = 0, a3 = 0;                                       \
    TAP(x0##M##a,  x0##M##b,  0) TAP(x0##Cc##a, x0##Cc##b, 1) TAP(x0##P##a, x0##P##b, 2) \
    TAP(x1##M##a,  x1##M##b,  3) TAP(x1##Cc##a, x1##Cc##b, 4) TAP(x1##P##a, x1##P##b, 5) \
    TAP(x2##M##a,  x2##M##b,  6) TAP(x2##Cc##a, x2##Cc##b, 7) TAP(x2##P##a, x2##P##b, 8) \
    int acc = (a0 + a1) + (a2 + a3);                                          \
    int v   = 2304 - 2 * acc - (cr);                                          \
    *(yptr) = (short)v;                                                       \
    s += v; q += __mul24(v, v);                                               \
} while (0)

__global__ __launch_bounds__(256, 2) void bconv_kernel(const uint32_t* __restrict__ px,
                                                       const uint32_t* __restrict__ wp,
                                                       const int* __restrict__ corr,
                                                       const uint32_t* __restrict__ zero_row,
                                                       short* __restrict__ y16t,
                                                       long long* __restrict__ sums,
                                                       long long* __restrict__ sumsq) {
    __shared__ uint4 xs[3][XS_COLS * 2];     // [row][colslot*2 + half], 5568 B
    int o   = threadIdx.x;          // output channel 0..255
    int blk = blockIdx.x;           // 0..1791
    int n = blk / HW, h = blk - n * HW;

    // --- stage 3 rows (+ zero halos) into LDS; all 256 threads cooperate ---
    {
        const uint32_t* rowb = px + (size_t)(n * P_PIX) * WPC;
        const uint32_t* rsrc0 = (h > 0)      ? rowb + (h - 1) * HW * WPC : zero_row;
        const uint32_t* rsrc1 = rowb + h * HW * WPC;
        const uint32_t* rsrc2 = (h < HW - 1) ? rowb + (h + 1) * HW * WPC : zero_row;
        for (int i = threadIdx.x; i < 348; i += 256) {
            if (i < 336) {
                int r  = i / 112;           // row 0..2
                int c4 = i - r * 112;       // uint4 index within row (112 = 56*8/4)
                const uint32_t* src = (r == 0 ? rsrc0 : (r == 1 ? rsrc1 : rsrc2)) + c4 * 4;
                xs[r][2 + c4] = *(const uint4*)src;   // halo col 0 occupies slots 0..1
            } else {
                int j = i - 336;            // 0..11: 3 rows x {colslot0 lo/hi, colslot57 lo/hi}
                int r = j >> 2;
                int k = j & 3;
                int idx = (k < 2) ? k : (57 * 2 + (k - 2));
                xs[r][idx] = make_uint4(0u, 0u, 0u, 0u);
            }
        }
    }

    uint32_t wreg[72];
    {
        const uint4* wq = (const uint4*)(wp + o * 72);
#pragma unroll
        for (int j = 0; j < 18; ++j) {
            uint4 t4 = wq[j];
            wreg[4*j+0] = t4.x; wreg[4*j+1] = t4.y;
            wreg[4*j+2] = t4.z; wreg[4*j+3] = t4.w;
        }
    }
    int vc  = (h == 0) ? 1 : ((h == HW - 1) ? 2 : 0);
    int crM = corr[o * 9 + vc * 3 + 0];
    int crL = corr[o * 9 + vc * 3 + 1];
    int crR = corr[o * 9 + vc * 3 + 2];

    __syncthreads();   // LDS staged

    uint4 x0Aa, x0Ab, x1Aa, x1Ab, x2Aa, x2Ab;
    uint4 x0Ba, x0Bb, x1Ba, x1Bb, x2Ba, x2Bb;
    uint4 x0Ca, x0Cb, x1Ca, x1Cb, x2Ca, x2Cb;

    short* yw = y16t + ((size_t)(n * P_PIX + h * HW)) * OC + o;
    int s = 0, q = 0;

    // w = 0 (slots 0,1,2)
    LOADCOL(A, 0); LOADCOL(B, 1); LOADCOL(C, 2);
    STEP(A, B, C, crL, yw);
    LOADCOL(A, 3);
    yw += OC;

    // interior w = 1..54, rotation x 3 (18 iterations)
    for (int wb = 1; wb <= 52; wb += 3) {
        STEP(B, C, A, crM, yw);          LOADCOL(B, wb + 3);
        STEP(C, A, B, crM, yw + OC);     LOADCOL(C, wb + 4);
        STEP(A, B, C, crM, yw + 2 * OC); LOADCOL(A, wb + 5);
        yw += 3 * OC;
    }

    // w = 55: cols 54,55,56 -> slots 55(B),56(C),57(A=halo zeros)
    STEP(B, C, A, crR, yw);

    atomicAdd((unsigned long long*)&sums[o],  (unsigned long long)(long long)s);
    atomicAdd((unsigned long long*)&sumsq[o], (unsigned long long)(long long)q);
}

// ---------------------------------------------------------------------------
// 4) Fused BN + Hardtanh + transpose back to NCHW through LDS.
//    Block = 64 pixels x 256 channels (49 blocks per image, never crosses n).
__global__ __launch_bounds__(256) void apply_kernel(const short* __restrict__ y16t,
                                                    float* __restrict__ out,
                                                    const long long* __restrict__ sums,
                                                    const long long* __restrict__ sumsq,
                                                    const float* __restrict__ gamma,
                                                    const float* __restrict__ beta) {
    __shared__ float sbf[512];               // scale[256] | bias[256]
    __shared__ uint32_t tile[64 * 129];      // short2-packed [px][ch/2], stride 129 dwords
    int t = threadIdx.x;
    {
        int o = t;
        double invN = 1.0 / NTOT;
        double mean = (double)sums[o] * invN;
        double var  = (double)sumsq[o] * invN - mean * mean;
        double sc   = (double)gamma[o] / sqrt(var + 1e-5);
        sbf[o]       = (float)sc;
        sbf[256 + o] = (float)((double)beta[o] - mean * sc);
    }
    int blk = blockIdx.x;                    // 0..1567
    int n   = blk / 49;
    int pl0 = (blk - n * 49) * 64;
    size_t P0 = (size_t)n * P_PIX + pl0;
    // phase A: load 64 px x 256 ch (coalesced short8), scatter into LDS as dwords
#pragma unroll
    for (int r = 0; r < 8; ++r) {
        int f8  = r * 256 + t;               // short8 units
        int pxl = f8 >> 5;
        int c8  = f8 & 31;
        uint4 v = *(const uint4*)(y16t + (P0 + pxl) * OC + c8 * 8);
        uint32_t* d = &tile[pxl * 129 + c8 * 4];
        d[0] = v.x; d[1] = v.y; d[2] = v.z; d[3] = v.w;
    }
    __syncthreads();
    // phase B: lane l -> ch = i*16 + wave*4 + l/16, px-quad = (l&15)*4
    int lane = t & 63, wv = t >> 6;
    int lp = lane & 15, lc = lane >> 4;
    int px0 = lp * 4;
#pragma unroll
    for (int i = 0; i < 16; ++i) {
        int ch = i * 16 + wv * 4 + lc;
        float sc = sbf[ch], bi = sbf[256 + ch];
        int sh = (ch & 1) << 4;
        int ci = ch >> 1;
        float4 ov;
        {
            int v0 = (int)(short)(tile[(px0 + 0) * 129 + ci] >> sh);
            int v1 = (int)(short)(tile[(px0 + 1) * 129 + ci] >> sh);
            int v2 = (int)(short)(tile[(px0 + 2) * 129 + ci] >> sh);
            int v3 = (int)(short)(tile[(px0 + 3) * 129 + ci] >> sh);
            ov.x = fminf(fmaxf(fmaf((float)v0, sc, bi), -1.0f), 1.0f);
            ov.y = fminf(fmaxf(fmaf((float)v1, sc, bi), -1.0f), 1.0f);
            ov.z = fminf(fmaxf(fmaf((float)v2, sc, bi), -1.0f), 1.0f);
            ov.w = fminf(fmaxf(fmaf((float)v3, sc, bi), -1.0f), 1.0f);
        }
        *(float4*)(out + ((size_t)(n * OC + ch)) * P_PIX + pl0 + px0) = ov;
    }
}

// ---------------------------------------------------------------------------
extern "C" void kernel_launch(void* const* d_in, const int* in_sizes, int n_in,
                              void* d_out, int out_size, void* d_ws, size_t ws_size,
                              hipStream_t stream) {
    const float* x     = (const float*)d_in[0];
    const float* Wt    = (const float*)d_in[1];
    const float* gamma = (const float*)d_in[2];
    const float* beta  = (const float*)d_in[3];
    float* out = (float*)d_out;
    char* ws = (char*)d_ws;

    // Workspace layout (total 54,680,576 B — proven available)
    uint32_t*  px       = (uint32_t*) (ws);              // 3,211,264
    uint32_t*  wp       = (uint32_t*) (ws + 3211264);    //    73,728
    int*       corr     = (int*)      (ws + 3284992);    //     9,216
    long long* sums     = (long long*)(ws + 3294208);    //     2,048
    long long* sumsq    = (long long*)(ws + 3296256);    //     2,048
    uint32_t*  zero_row = (uint32_t*) (ws + 3298304);    //     2,048 (1792 used)
    short*     y16t     = (short*)    (ws + 3300352);    // 51,380,224

    hipLaunchKernelGGL(pack_x_kernel, dim3(393),  dim3(256), 0, stream, x, px, zero_row);
    hipLaunchKernelGGL(pack_w_kernel, dim3(OC),   dim3(128), 0, stream, Wt, wp, corr, sums, sumsq);
    hipLaunchKernelGGL(bconv_kernel,  dim3(1792), dim3(256), 0, stream, px, wp, corr, zero_row,
                       y16t, sums, sumsq);
    hipLaunchKernelGGL(apply_kernel,  dim3(1568), dim3(256), 0, stream, y16t, out,
                       sums, sumsq, gamma, beta);
}